// Round 7
// baseline (852.004 us; speedup 1.0000x reference)
//
#include <hip/hip_runtime.h>
#include <hip/hip_bf16.h>

// NGCF forward on MI355X.
// CSR via two-pass bucket radix: k_bin stages edges into 128-row-bucket cells.
// NREP=8 replica cells selected by blockIdx&7 == XCD id under round-robin
// dispatch -> each staging cache line is written by ONE XCD's L2 only and
// evicted once (fixes the 6x cross-XCD partial-line write amplification seen
// in r6: WRITE_SIZE 223MB for 38.4MB logical). k_sortbucket counting-sorts
// each bucket in LDS and writes its CSR segment coalesced. Per layer:
// k_spmm4 (register-accumulate SpMM, 4 rows/wave), k_dense (MFMA 16x16x32
// bf16), k_gather (normalize+pick 8192 rows). Dtype detected at runtime.

#define N_USER 100000
#define N_ITEM 50000
#define N_NODES 150000
#define NE 4800000
#define D 64
#define BROWS 128
#define NBUCK ((N_NODES + BROWS - 1) / BROWS)  // 1172
#define NREP 8
#define CAP 768                                 // per-cell: mean 512 + 11 sigma
#define BCAP 4480                               // per-bucket: mean 4096 + 6 sigma
#define DG_BLOCKS 1024                          // dense grid
#define NG (N_NODES / 16)                       // 9375 row-groups of 16

typedef __hip_bfloat16 bf16;
typedef unsigned short u16;
typedef __attribute__((ext_vector_type(8))) short short8;
typedef __attribute__((ext_vector_type(4))) float float4v;

__device__ __forceinline__ float bits2f(u16 u) {
  return __uint_as_float(((unsigned int)u) << 16);
}
__device__ __forceinline__ u16 f2bits(float x) {
  union { bf16 h; u16 u; } c;
  c.h = __float2bfloat16(x);
  return c.u;
}
__device__ __forceinline__ float loadF(const void* p, long i, int f32) {
  if (f32) return ((const float*)p)[i];
  return bits2f(((const u16*)p)[i]);
}

__global__ void k_zero(int* __restrict__ p, int n) {
  int i = blockIdx.x * blockDim.x + threadIdx.x;
  if (i < n) p[i] = 0;
}

// flag <- 1 if the float buffers are float32, 0 if bf16.
__global__ void k_detect(const u16* __restrict__ ue, int* __restrict__ flag) {
  int bad = 0;
  for (int t = threadIdx.x; t < 512; t += 256) {
    float f = fabsf(bits2f(ue[t]));
    if (!(f < 1e4f)) bad = 1;  // catches NaN/Inf too
  }
  if (bad) atomicOr(flag, 1);
}

// ego32[N,64] fp32 and egobf[N,64] bf16 <- concat(user_emb, item_emb)
__global__ void k_init(const void* __restrict__ ue, const void* __restrict__ ie,
                       float* __restrict__ ego32, u16* __restrict__ egobf,
                       const int* __restrict__ flag) {
  int f32 = *flag;
  int i4 = (blockIdx.x * blockDim.x + threadIdx.x) * 4;
  if (i4 >= N_NODES * D) return;
  const int UD = N_USER * D;
  float4 v;
  ushort4 b;
  if (f32) {
    const float* s = (i4 < UD) ? ((const float*)ue + i4) : ((const float*)ie + (i4 - UD));
    v = *(const float4*)s;
    b = make_ushort4(f2bits(v.x), f2bits(v.y), f2bits(v.z), f2bits(v.w));
  } else {
    const u16* s = (i4 < UD) ? ((const u16*)ue + i4) : ((const u16*)ie + (i4 - UD));
    b = *(const ushort4*)s;
    v = make_float4(bits2f(b.x), bits2f(b.y), bits2f(b.z), bits2f(b.w));
  }
  *(float4*)(ego32 + i4) = v;
  *(ushort4*)(egobf + i4) = b;
}

// Bin edges into bucket staging. Entry: (local_row<<18 | col, val_bits).
// rep = blockIdx&7 -> one XCD per cell under round-robin dispatch.
__global__ void k_bin(const int* __restrict__ row, const int* __restrict__ col,
                      const void* __restrict__ val, int* __restrict__ bcnt,
                      int2* __restrict__ staged, const int* __restrict__ flag) {
  int f32 = *flag;
  int e = blockIdx.x * blockDim.x + threadIdx.x;
  if (e >= NE) return;
  int r = row[e];
  int c = col[e];
  float v = loadF(val, e, f32);
  int b = r >> 7;
  int lr = r & 127;
  int cell = b * NREP + (blockIdx.x & (NREP - 1));
  int pos = atomicAdd(&bcnt[cell], 1);
  if (pos >= CAP) pos = CAP - 1;  // statistically unreachable (mean+11σ cap)
  staged[(size_t)cell * CAP + pos] = make_int2((lr << 18) | c, __float_as_int(v));
}

// Exclusive scan of per-bucket totals -> bbase[NBUCK]. One block of 1024.
__global__ void __launch_bounds__(1024) k_bucketbase(const int* __restrict__ bcnt,
                                                     int* __restrict__ bbase) {
  __shared__ int sh[2048];
  int tid = threadIdx.x;
  int t0 = 0, t1 = 0;
  if (tid < NBUCK) {
    for (int rep = 0; rep < NREP; ++rep) t0 += min(bcnt[tid * NREP + rep], CAP);
  }
  int i1 = 1024 + tid;
  if (i1 < NBUCK) {
    for (int rep = 0; rep < NREP; ++rep) t1 += min(bcnt[i1 * NREP + rep], CAP);
  }
  sh[tid] = t0;
  sh[i1] = t1;
  __syncthreads();
  for (int off = 1; off < 2048; off <<= 1) {
    int a0 = (tid >= off) ? sh[tid - off] : 0;
    int a1 = (i1 >= off) ? sh[i1 - off] : 0;
    __syncthreads();
    sh[tid] += a0;
    sh[i1] += a1;
    __syncthreads();
  }
  if (tid < NBUCK) bbase[tid] = sh[tid] - t0;       // exclusive
  if (i1 < NBUCK) bbase[i1] = sh[i1] - t1;
}

// One block per bucket: LDS counting sort of the bucket's staged edges, then
// coalesced sequential write of the contiguous CSR segment + rp.
__global__ void __launch_bounds__(256) k_sortbucket(
    const int* __restrict__ bcnt, const int2* __restrict__ staged,
    const int* __restrict__ bbase, int* __restrict__ rp, int2* __restrict__ csr) {
  __shared__ int2 sbuf[BCAP];      // 35.8 KB
  __shared__ int hist[BROWS];
  __shared__ int cursor[BROWS];
  __shared__ int scantmp[BROWS];
  int tid = threadIdx.x;
  int b = blockIdx.x;
  if (tid < BROWS) hist[tid] = 0;
  __syncthreads();

  for (int rep = 0; rep < NREP; ++rep) {
    int cell = b * NREP + rep;
    int n = min(bcnt[cell], CAP);
    const int2* seg = staged + (size_t)cell * CAP;
    for (int i = tid; i < n; i += 256) atomicAdd(&hist[seg[i].x >> 18], 1);
  }
  __syncthreads();

  if (tid < BROWS) scantmp[tid] = hist[tid];
  __syncthreads();
  for (int off = 1; off < BROWS; off <<= 1) {
    int v = (tid < BROWS && tid >= off) ? scantmp[tid - off] : 0;
    __syncthreads();
    if (tid < BROWS) scantmp[tid] += v;   // inclusive
    __syncthreads();
  }
  int base_b = bbase[b];
  if (tid < BROWS) {
    int ex = scantmp[tid] - hist[tid];    // exclusive start within bucket
    cursor[tid] = ex;
    int r = b * BROWS + tid;
    if (r < N_NODES) rp[r] = base_b + ex;
  }
  if (b == 0 && tid == 0) rp[N_NODES] = NE;
  __syncthreads();

  for (int rep = 0; rep < NREP; ++rep) {
    int cell = b * NREP + rep;
    int n = min(bcnt[cell], CAP);
    const int2* seg = staged + (size_t)cell * CAP;
    for (int i = tid; i < n; i += 256) {
      int2 ent = seg[i];
      int lr = ent.x >> 18;
      int pos = atomicAdd(&cursor[lr], 1);
      if (pos < BCAP) sbuf[pos] = make_int2(ent.x & 0x3FFFF, ent.y);
    }
  }
  __syncthreads();

  int tot = min(scantmp[BROWS - 1], BCAP);
  for (int i = tid; i < tot; i += 256) csr[(size_t)base_b + i] = sbuf[i];
}

// 4 rows per wave (quarter-wave q = 16 lanes x ushort4 = one row).
// side = sum val*egobf[col]; prod = ego32[r]*side; write bf16 [side|prod].
__global__ void __launch_bounds__(256) k_spmm4(
    const int* __restrict__ rp, const int2* __restrict__ csr,
    const u16* __restrict__ egobf, const float* __restrict__ ego32,
    u16* __restrict__ spbf) {
  int tid = threadIdx.x;
  int wid = (blockIdx.x * 256 + tid) >> 6;
  int q = (tid >> 4) & 3;
  int ln = tid & 15;
  int r = wid * 4 + q;
  bool act = r < N_NODES;
  int rr = act ? r : 0;
  int s = rp[rr];
  int e = act ? rp[rr + 1] : s;

  float4 acc = make_float4(0.f, 0.f, 0.f, 0.f);
  int i = s;
  for (; i + 8 <= e; i += 8) {
    int2 cc[8];
#pragma unroll
    for (int t = 0; t < 8; ++t) cc[t] = csr[i + t];
    ushort4 gg[8];
#pragma unroll
    for (int t = 0; t < 8; ++t)
      gg[t] = *(const ushort4*)(egobf + (size_t)cc[t].x * 64 + ln * 4);
#pragma unroll
    for (int t = 0; t < 8; ++t) {
      float v = __int_as_float(cc[t].y);
      acc.x += v * bits2f(gg[t].x);
      acc.y += v * bits2f(gg[t].y);
      acc.z += v * bits2f(gg[t].z);
      acc.w += v * bits2f(gg[t].w);
    }
  }
  for (; i < e; ++i) {
    int2 c = csr[i];
    ushort4 g = *(const ushort4*)(egobf + (size_t)c.x * 64 + ln * 4);
    float v = __int_as_float(c.y);
    acc.x += v * bits2f(g.x);
    acc.y += v * bits2f(g.y);
    acc.z += v * bits2f(g.z);
    acc.w += v * bits2f(g.w);
  }
  if (act) {
    float4 er = *(const float4*)(ego32 + (size_t)r * 64 + ln * 4);
    u16* o = spbf + (size_t)r * 128 + ln * 4;
    *(ushort4*)o = make_ushort4(f2bits(acc.x), f2bits(acc.y), f2bits(acc.z), f2bits(acc.w));
    *(ushort4*)(o + 64) = make_ushort4(f2bits(er.x * acc.x), f2bits(er.y * acc.y),
                                       f2bits(er.z * acc.z), f2bits(er.w * acc.w));
  }
}

// ego_out = leaky_relu([side|prod] @ [Wg;Wb] + (bg+bb)) via MFMA 16x16x32 bf16.
// One wave = 16 rows x 64 cols; B-frags (4 col-tiles x 4 K-steps) in VGPRs.
// A-frag: A[m=lane&15][k=quad*8+j]; C/D: col=lane&15, row=quad*4+reg.
__global__ void __launch_bounds__(256) k_dense(
    const u16* __restrict__ spbf, const void* __restrict__ Wgc,
    const void* __restrict__ bgc, const void* __restrict__ Wbi,
    const void* __restrict__ bbi, float* __restrict__ ego32,
    u16* __restrict__ egobf, int layer, const int* __restrict__ flag) {
  __shared__ u16 sW[8192];   // frag-ordered [t][s2][lane][j]
  __shared__ float sbias[64];
  int f32 = *flag;
  int tid = threadIdx.x;
  for (int f = tid; f < 8192; f += 256) {
    int j = f & 7;
    int lane = (f >> 3) & 63;
    int s2 = (f >> 9) & 3;
    int t = f >> 11;
    int k = s2 * 32 + (lane >> 4) * 8 + j;
    int n = t * 16 + (lane & 15);
    float w = (k < 64) ? loadF(Wgc, (long)layer * 4096 + k * 64 + n, f32)
                       : loadF(Wbi, (long)layer * 4096 + (k - 64) * 64 + n, f32);
    sW[f] = f2bits(w);
  }
  if (tid < 64)
    sbias[tid] = loadF(bgc, layer * 64 + tid, f32) + loadF(bbi, layer * 64 + tid, f32);
  __syncthreads();

  int lane = tid & 63;
  int ln = lane & 15;
  int quad = lane >> 4;
  int gwave = blockIdx.x * 4 + (tid >> 6);

  short8 B[4][4];
#pragma unroll
  for (int t = 0; t < 4; ++t)
#pragma unroll
    for (int s2 = 0; s2 < 4; ++s2)
      B[t][s2] = *(const short8*)(sW + ((size_t)((t * 4 + s2) * 64 + lane)) * 8);

  float bt[4];
#pragma unroll
  for (int t = 0; t < 4; ++t) bt[t] = sbias[t * 16 + ln];

  for (int g = gwave; g < NG; g += DG_BLOCKS * 4) {
    int r0 = g * 16;
    float4v acc[4];
#pragma unroll
    for (int t = 0; t < 4; ++t) acc[t] = (float4v){0.f, 0.f, 0.f, 0.f};
#pragma unroll
    for (int s2 = 0; s2 < 4; ++s2) {
      short8 A = *(const short8*)(spbf + (size_t)(r0 + ln) * 128 + s2 * 32 + quad * 8);
#pragma unroll
      for (int t = 0; t < 4; ++t)
        acc[t] = __builtin_amdgcn_mfma_f32_16x16x32_bf16(A, B[t][s2], acc[t], 0, 0, 0);
    }
#pragma unroll
    for (int t = 0; t < 4; ++t) {
#pragma unroll
      for (int g2 = 0; g2 < 4; ++g2) {
        float x = acc[t][g2] + bt[t];
        x = fmaxf(x, 0.2f * x);  // leaky_relu(0.2)
        size_t idx = (size_t)(r0 + quad * 4 + g2) * 64 + t * 16 + ln;
        ego32[idx] = x;
        egobf[idx] = f2bits(x);
      }
    }
  }
}

// gather 8192 output rows into out slice; optional l2-normalize per row.
__global__ void k_gather(const float* __restrict__ ego, const int* __restrict__ users,
                         const int* __restrict__ items, void* __restrict__ out,
                         int slice, int do_norm, const int* __restrict__ flag) {
  int f32 = *flag;
  int b = blockIdx.x * 4 + (threadIdx.x >> 6);
  int lane = threadIdx.x & 63;
  if (b >= 8192) return;
  int r = (b < 4096) ? users[b] : (N_USER + items[b - 4096]);
  float x = ego[(size_t)r * D + lane];
  float scale = 1.f;
  if (do_norm) {
    float ss = x * x;
    for (int off = 32; off > 0; off >>= 1) ss += __shfl_xor(ss, off);
    scale = 1.f / fmaxf(sqrtf(ss), 1e-12f);
  }
  float y = x * scale;
  long idx = (long)b * 256 + slice * 64 + lane;
  if (f32) ((float*)out)[idx] = y;
  else ((bf16*)out)[idx] = __float2bfloat16(y);
}

extern "C" void kernel_launch(void* const* d_in, const int* in_sizes, int n_in,
                              void* d_out, int out_size, void* d_ws, size_t ws_size,
                              hipStream_t stream) {
  const void* ue = d_in[0];
  const void* ie = d_in[1];
  const void* Wgc = d_in[2];
  const void* bgc = d_in[3];
  const void* Wbi = d_in[4];
  const void* bbi = d_in[5];
  const void* aval = d_in[6];
  const int* arow = (const int*)d_in[7];
  const int* acol = (const int*)d_in[8];
  const int* users = (const int*)d_in[9];
  const int* items = (const int*)d_in[10];

  char* ws = (char*)d_ws;
  size_t off = 0;
  float* ego32 = (float*)(ws + off);  off += (size_t)N_NODES * D * 4;          // 38.4 MB
  u16* egobf = (u16*)(ws + off);      off += (size_t)N_NODES * D * 2;          // 19.2 MB
  u16* spbf = (u16*)(ws + off);       off += (size_t)N_NODES * 128 * 2;        // 38.4 MB
  int2* staged = (int2*)(ws + off);   off += (size_t)NBUCK * NREP * CAP * 8;   // 57.6 MB
  int2* csr = (int2*)(ws + off);      off += (size_t)NE * 8;                   // 38.4 MB
  int* rp = (int*)(ws + off);         off += (size_t)(N_NODES + 64) * 4;
  int* bcnt = (int*)(ws + off);       off += (size_t)NBUCK * NREP * 4;
  int* bbase = (int*)(ws + off);      off += (size_t)(NBUCK + 64) * 4;
  int* flag = (int*)(ws + off);       off += 256;
  (void)ws_size;

  k_zero<<<1, 64, 0, stream>>>(flag, 1);
  k_detect<<<1, 256, 0, stream>>>((const u16*)ue, flag);
  k_zero<<<(NBUCK * NREP + 255) / 256, 256, 0, stream>>>(bcnt, NBUCK * NREP);
  k_init<<<(N_NODES * D / 4 + 255) / 256, 256, 0, stream>>>(ue, ie, ego32, egobf, flag);
  // slice 0 = raw (un-normalized) initial ego
  k_gather<<<2048, 256, 0, stream>>>(ego32, users, items, d_out, 0, 0, flag);
  k_bin<<<(NE + 255) / 256, 256, 0, stream>>>(arow, acol, aval, bcnt, staged, flag);
  k_bucketbase<<<1, 1024, 0, stream>>>(bcnt, bbase);
  k_sortbucket<<<NBUCK, 256, 0, stream>>>(bcnt, staged, bbase, rp, csr);

  for (int k = 0; k < 3; ++k) {
    k_spmm4<<<(N_NODES / 4 + 3) / 4 + 1, 256, 0, stream>>>(rp, csr, egobf, ego32, spbf);
    k_dense<<<DG_BLOCKS, 256, 0, stream>>>(spbf, Wgc, bgc, Wbi, bbi, ego32, egobf, k, flag);
    k_gather<<<2048, 256, 0, stream>>>(ego32, users, items, d_out, k + 1, 1, flag);
  }
}

// Round 8
// 680.544 us; speedup vs baseline: 1.2519x; 1.2519x over previous
//
#include <hip/hip_runtime.h>
#include <hip/hip_bf16.h>

// NGCF forward on MI355X.
// CSR via block-aggregated bucket binning: each block histograms an 8192-edge
// chunk over the 1172 row-buckets in LDS, reserves per-bucket runs with ONE
// global atomicAdd per (block,bucket) (global atomics are the hidden cost:
// ~42B HBM RMW each on this chiplet part - r4/r6/r7 WRITE_SIZE evidence),
// then scatters entries via LDS cursors into per-bucket contiguous staging
// (dense, single-block runs). k_sortbucket counting-sorts each bucket in LDS
// and writes its CSR segment coalesced. Per layer: k_spmm4 (register-
// accumulate SpMM, 4 rows/wave), k_dense (MFMA 16x16x32 bf16), k_gather
// (normalize+pick 8192 rows). Float dtype detected at runtime.

#define N_USER 100000
#define N_ITEM 50000
#define N_NODES 150000
#define NE 4800000
#define D 64
#define BROWS 128
#define NBUCK ((N_NODES + BROWS - 1) / BROWS)  // 1172
#define CHUNK 8192
#define BINB ((NE + CHUNK - 1) / CHUNK)        // 586 binning blocks
#define BCAP 4480                               // per-bucket: mean 4096 + 6 sigma
#define DG_BLOCKS 1024                          // dense grid
#define NG (N_NODES / 16)                       // 9375 row-groups of 16

typedef __hip_bfloat16 bf16;
typedef unsigned short u16;
typedef __attribute__((ext_vector_type(8))) short short8;
typedef __attribute__((ext_vector_type(4))) float float4v;

__device__ __forceinline__ float bits2f(u16 u) {
  return __uint_as_float(((unsigned int)u) << 16);
}
__device__ __forceinline__ u16 f2bits(float x) {
  union { bf16 h; u16 u; } c;
  c.h = __float2bfloat16(x);
  return c.u;
}
__device__ __forceinline__ float loadF(const void* p, long i, int f32) {
  if (f32) return ((const float*)p)[i];
  return bits2f(((const u16*)p)[i]);
}

__global__ void k_zero(int* __restrict__ p, int n) {
  int i = blockIdx.x * blockDim.x + threadIdx.x;
  if (i < n) p[i] = 0;
}

// flag <- 1 if the float buffers are float32, 0 if bf16.
__global__ void k_detect(const u16* __restrict__ ue, int* __restrict__ flag) {
  int bad = 0;
  for (int t = threadIdx.x; t < 512; t += 256) {
    float f = fabsf(bits2f(ue[t]));
    if (!(f < 1e4f)) bad = 1;  // catches NaN/Inf too
  }
  if (bad) atomicOr(flag, 1);
}

// ego32[N,64] fp32 and egobf[N,64] bf16 <- concat(user_emb, item_emb)
__global__ void k_init(const void* __restrict__ ue, const void* __restrict__ ie,
                       float* __restrict__ ego32, u16* __restrict__ egobf,
                       const int* __restrict__ flag) {
  int f32 = *flag;
  int i4 = (blockIdx.x * blockDim.x + threadIdx.x) * 4;
  if (i4 >= N_NODES * D) return;
  const int UD = N_USER * D;
  float4 v;
  ushort4 b;
  if (f32) {
    const float* s = (i4 < UD) ? ((const float*)ue + i4) : ((const float*)ie + (i4 - UD));
    v = *(const float4*)s;
    b = make_ushort4(f2bits(v.x), f2bits(v.y), f2bits(v.z), f2bits(v.w));
  } else {
    const u16* s = (i4 < UD) ? ((const u16*)ue + i4) : ((const u16*)ie + (i4 - UD));
    b = *(const ushort4*)s;
    v = make_float4(bits2f(b.x), bits2f(b.y), bits2f(b.z), bits2f(b.w));
  }
  *(float4*)(ego32 + i4) = v;
  *(ushort4*)(egobf + i4) = b;
}

// Block-aggregated binning. Entry: (local_row<<18 | col, val_bits).
__global__ void __launch_bounds__(256) k_bin(
    const int* __restrict__ row, const int* __restrict__ col,
    const void* __restrict__ val, int* __restrict__ bcnt,
    int2* __restrict__ staged, const int* __restrict__ flag) {
  __shared__ int hist[NBUCK];
  __shared__ int lcur[NBUCK];
  int f32 = *flag;
  int tid = threadIdx.x;
  int e0 = blockIdx.x * CHUNK;
  int e1 = min(e0 + CHUNK, NE);
  for (int i = tid; i < NBUCK; i += 256) hist[i] = 0;
  __syncthreads();
  // pass 1: per-chunk bucket histogram (LDS atomics)
  for (int e = e0 + tid; e < e1; e += 256) atomicAdd(&hist[row[e] >> 7], 1);
  __syncthreads();
  // reserve runs: one global atomic per non-empty (block,bucket)
  for (int i = tid; i < NBUCK; i += 256) {
    int h = hist[i];
    lcur[i] = h ? atomicAdd(&bcnt[i], h) : 0;
  }
  __syncthreads();
  // pass 2: scatter into per-bucket contiguous staging (L2-hot re-read)
  for (int e = e0 + tid; e < e1; e += 256) {
    int r = row[e];
    int b = r >> 7;
    int pos = atomicAdd(&lcur[b], 1);
    if (pos < BCAP)
      staged[(size_t)b * BCAP + pos] =
          make_int2(((r & 127) << 18) | col[e], __float_as_int(loadF(val, e, f32)));
  }
}

// Exclusive scan of per-bucket totals -> bbase[NBUCK]. One block of 1024.
__global__ void __launch_bounds__(1024) k_bucketbase(const int* __restrict__ bcnt,
                                                     int* __restrict__ bbase) {
  __shared__ int sh[2048];
  int tid = threadIdx.x;
  int t0 = (tid < NBUCK) ? min(bcnt[tid], BCAP) : 0;
  int i1 = 1024 + tid;
  int t1 = (i1 < NBUCK) ? min(bcnt[i1], BCAP) : 0;
  sh[tid] = t0;
  sh[i1] = t1;
  __syncthreads();
  for (int off = 1; off < 2048; off <<= 1) {
    int a0 = (tid >= off) ? sh[tid - off] : 0;
    int a1 = (i1 >= off) ? sh[i1 - off] : 0;
    __syncthreads();
    sh[tid] += a0;
    sh[i1] += a1;
    __syncthreads();
  }
  if (tid < NBUCK) bbase[tid] = sh[tid] - t0;       // exclusive
  if (i1 < NBUCK) bbase[i1] = sh[i1] - t1;
}

// One block per bucket: LDS counting sort of the bucket's staged edges, then
// coalesced sequential write of the contiguous CSR segment + rp.
__global__ void __launch_bounds__(256) k_sortbucket(
    const int* __restrict__ bcnt, const int2* __restrict__ staged,
    const int* __restrict__ bbase, int* __restrict__ rp, int2* __restrict__ csr) {
  __shared__ int2 sbuf[BCAP];      // 35.8 KB
  __shared__ int hist[BROWS];
  __shared__ int cursor[BROWS];
  __shared__ int scantmp[BROWS];
  int tid = threadIdx.x;
  int b = blockIdx.x;
  if (tid < BROWS) hist[tid] = 0;
  __syncthreads();

  int n = min(bcnt[b], BCAP);
  const int2* seg = staged + (size_t)b * BCAP;
  for (int i = tid; i < n; i += 256) atomicAdd(&hist[seg[i].x >> 18], 1);
  __syncthreads();

  if (tid < BROWS) scantmp[tid] = hist[tid];
  __syncthreads();
  for (int off = 1; off < BROWS; off <<= 1) {
    int v = (tid < BROWS && tid >= off) ? scantmp[tid - off] : 0;
    __syncthreads();
    if (tid < BROWS) scantmp[tid] += v;   // inclusive
    __syncthreads();
  }
  int base_b = bbase[b];
  if (tid < BROWS) {
    int ex = scantmp[tid] - hist[tid];    // exclusive start within bucket
    cursor[tid] = ex;
    int r = b * BROWS + tid;
    if (r < N_NODES) rp[r] = base_b + ex;
  }
  if (b == 0 && tid == 0) rp[N_NODES] = NE;
  __syncthreads();

  for (int i = tid; i < n; i += 256) {
    int2 ent = seg[i];
    int lr = ent.x >> 18;
    int pos = atomicAdd(&cursor[lr], 1);
    if (pos < BCAP) sbuf[pos] = make_int2(ent.x & 0x3FFFF, ent.y);
  }
  __syncthreads();

  int tot = min(scantmp[BROWS - 1], BCAP);
  for (int i = tid; i < tot; i += 256) csr[(size_t)base_b + i] = sbuf[i];
}

// 4 rows per wave (quarter-wave q = 16 lanes x ushort4 = one row).
// side = sum val*egobf[col]; prod = ego32[r]*side; write bf16 [side|prod].
__global__ void __launch_bounds__(256) k_spmm4(
    const int* __restrict__ rp, const int2* __restrict__ csr,
    const u16* __restrict__ egobf, const float* __restrict__ ego32,
    u16* __restrict__ spbf) {
  int tid = threadIdx.x;
  int wid = (blockIdx.x * 256 + tid) >> 6;
  int q = (tid >> 4) & 3;
  int ln = tid & 15;
  int r = wid * 4 + q;
  bool act = r < N_NODES;
  int rr = act ? r : 0;
  int s = rp[rr];
  int e = act ? rp[rr + 1] : s;

  float4 acc = make_float4(0.f, 0.f, 0.f, 0.f);
  int i = s;
  for (; i + 8 <= e; i += 8) {
    int2 cc[8];
#pragma unroll
    for (int t = 0; t < 8; ++t) cc[t] = csr[i + t];
    ushort4 gg[8];
#pragma unroll
    for (int t = 0; t < 8; ++t)
      gg[t] = *(const ushort4*)(egobf + (size_t)cc[t].x * 64 + ln * 4);
#pragma unroll
    for (int t = 0; t < 8; ++t) {
      float v = __int_as_float(cc[t].y);
      acc.x += v * bits2f(gg[t].x);
      acc.y += v * bits2f(gg[t].y);
      acc.z += v * bits2f(gg[t].z);
      acc.w += v * bits2f(gg[t].w);
    }
  }
  for (; i < e; ++i) {
    int2 c = csr[i];
    ushort4 g = *(const ushort4*)(egobf + (size_t)c.x * 64 + ln * 4);
    float v = __int_as_float(c.y);
    acc.x += v * bits2f(g.x);
    acc.y += v * bits2f(g.y);
    acc.z += v * bits2f(g.z);
    acc.w += v * bits2f(g.w);
  }
  if (act) {
    float4 er = *(const float4*)(ego32 + (size_t)r * 64 + ln * 4);
    u16* o = spbf + (size_t)r * 128 + ln * 4;
    *(ushort4*)o = make_ushort4(f2bits(acc.x), f2bits(acc.y), f2bits(acc.z), f2bits(acc.w));
    *(ushort4*)(o + 64) = make_ushort4(f2bits(er.x * acc.x), f2bits(er.y * acc.y),
                                       f2bits(er.z * acc.z), f2bits(er.w * acc.w));
  }
}

// ego_out = leaky_relu([side|prod] @ [Wg;Wb] + (bg+bb)) via MFMA 16x16x32 bf16.
// One wave = 16 rows x 64 cols; B-frags (4 col-tiles x 4 K-steps) in VGPRs.
// A-frag: A[m=lane&15][k=quad*8+j]; C/D: col=lane&15, row=quad*4+reg.
__global__ void __launch_bounds__(256) k_dense(
    const u16* __restrict__ spbf, const void* __restrict__ Wgc,
    const void* __restrict__ bgc, const void* __restrict__ Wbi,
    const void* __restrict__ bbi, float* __restrict__ ego32,
    u16* __restrict__ egobf, int layer, const int* __restrict__ flag) {
  __shared__ u16 sW[8192];   // frag-ordered [t][s2][lane][j]
  __shared__ float sbias[64];
  int f32 = *flag;
  int tid = threadIdx.x;
  for (int f = tid; f < 8192; f += 256) {
    int j = f & 7;
    int lane = (f >> 3) & 63;
    int s2 = (f >> 9) & 3;
    int t = f >> 11;
    int k = s2 * 32 + (lane >> 4) * 8 + j;
    int n = t * 16 + (lane & 15);
    float w = (k < 64) ? loadF(Wgc, (long)layer * 4096 + k * 64 + n, f32)
                       : loadF(Wbi, (long)layer * 4096 + (k - 64) * 64 + n, f32);
    sW[f] = f2bits(w);
  }
  if (tid < 64)
    sbias[tid] = loadF(bgc, layer * 64 + tid, f32) + loadF(bbi, layer * 64 + tid, f32);
  __syncthreads();

  int lane = tid & 63;
  int ln = lane & 15;
  int quad = lane >> 4;
  int gwave = blockIdx.x * 4 + (tid >> 6);

  short8 B[4][4];
#pragma unroll
  for (int t = 0; t < 4; ++t)
#pragma unroll
    for (int s2 = 0; s2 < 4; ++s2)
      B[t][s2] = *(const short8*)(sW + ((size_t)((t * 4 + s2) * 64 + lane)) * 8);

  float bt[4];
#pragma unroll
  for (int t = 0; t < 4; ++t) bt[t] = sbias[t * 16 + ln];

  for (int g = gwave; g < NG; g += DG_BLOCKS * 4) {
    int r0 = g * 16;
    float4v acc[4];
#pragma unroll
    for (int t = 0; t < 4; ++t) acc[t] = (float4v){0.f, 0.f, 0.f, 0.f};
#pragma unroll
    for (int s2 = 0; s2 < 4; ++s2) {
      short8 A = *(const short8*)(spbf + (size_t)(r0 + ln) * 128 + s2 * 32 + quad * 8);
#pragma unroll
      for (int t = 0; t < 4; ++t)
        acc[t] = __builtin_amdgcn_mfma_f32_16x16x32_bf16(A, B[t][s2], acc[t], 0, 0, 0);
    }
#pragma unroll
    for (int t = 0; t < 4; ++t) {
#pragma unroll
      for (int g2 = 0; g2 < 4; ++g2) {
        float x = acc[t][g2] + bt[t];
        x = fmaxf(x, 0.2f * x);  // leaky_relu(0.2)
        size_t idx = (size_t)(r0 + quad * 4 + g2) * 64 + t * 16 + ln;
        ego32[idx] = x;
        egobf[idx] = f2bits(x);
      }
    }
  }
}

// gather 8192 output rows into out slice; optional l2-normalize per row.
__global__ void k_gather(const float* __restrict__ ego, const int* __restrict__ users,
                         const int* __restrict__ items, void* __restrict__ out,
                         int slice, int do_norm, const int* __restrict__ flag) {
  int f32 = *flag;
  int b = blockIdx.x * 4 + (threadIdx.x >> 6);
  int lane = threadIdx.x & 63;
  if (b >= 8192) return;
  int r = (b < 4096) ? users[b] : (N_USER + items[b - 4096]);
  float x = ego[(size_t)r * D + lane];
  float scale = 1.f;
  if (do_norm) {
    float ss = x * x;
    for (int off = 32; off > 0; off >>= 1) ss += __shfl_xor(ss, off);
    scale = 1.f / fmaxf(sqrtf(ss), 1e-12f);
  }
  float y = x * scale;
  long idx = (long)b * 256 + slice * 64 + lane;
  if (f32) ((float*)out)[idx] = y;
  else ((bf16*)out)[idx] = __float2bfloat16(y);
}

extern "C" void kernel_launch(void* const* d_in, const int* in_sizes, int n_in,
                              void* d_out, int out_size, void* d_ws, size_t ws_size,
                              hipStream_t stream) {
  const void* ue = d_in[0];
  const void* ie = d_in[1];
  const void* Wgc = d_in[2];
  const void* bgc = d_in[3];
  const void* Wbi = d_in[4];
  const void* bbi = d_in[5];
  const void* aval = d_in[6];
  const int* arow = (const int*)d_in[7];
  const int* acol = (const int*)d_in[8];
  const int* users = (const int*)d_in[9];
  const int* items = (const int*)d_in[10];

  char* ws = (char*)d_ws;
  size_t off = 0;
  float* ego32 = (float*)(ws + off);  off += (size_t)N_NODES * D * 4;     // 38.4 MB
  u16* egobf = (u16*)(ws + off);      off += (size_t)N_NODES * D * 2;     // 19.2 MB
  u16* spbf = (u16*)(ws + off);       off += (size_t)N_NODES * 128 * 2;   // 38.4 MB
  int2* staged = (int2*)(ws + off);   off += (size_t)NBUCK * BCAP * 8;    // 42.0 MB
  int2* csr = (int2*)(ws + off);      off += (size_t)NE * 8;              // 38.4 MB
  int* rp = (int*)(ws + off);         off += (size_t)(N_NODES + 64) * 4;
  int* bcnt = (int*)(ws + off);       off += (size_t)NBUCK * 4;
  int* bbase = (int*)(ws + off);      off += (size_t)(NBUCK + 64) * 4;
  int* flag = (int*)(ws + off);       off += 256;
  (void)ws_size;

  k_zero<<<1, 64, 0, stream>>>(flag, 1);
  k_detect<<<1, 256, 0, stream>>>((const u16*)ue, flag);
  k_zero<<<(NBUCK + 255) / 256, 256, 0, stream>>>(bcnt, NBUCK);
  k_init<<<(N_NODES * D / 4 + 255) / 256, 256, 0, stream>>>(ue, ie, ego32, egobf, flag);
  // slice 0 = raw (un-normalized) initial ego
  k_gather<<<2048, 256, 0, stream>>>(ego32, users, items, d_out, 0, 0, flag);
  k_bin<<<BINB, 256, 0, stream>>>(arow, acol, aval, bcnt, staged, flag);
  k_bucketbase<<<1, 1024, 0, stream>>>(bcnt, bbase);
  k_sortbucket<<<NBUCK, 256, 0, stream>>>(bcnt, staged, bbase, rp, csr);

  for (int k = 0; k < 3; ++k) {
    k_spmm4<<<(N_NODES / 4 + 3) / 4 + 1, 256, 0, stream>>>(rp, csr, egobf, ego32, spbf);
    k_dense<<<DG_BLOCKS, 256, 0, stream>>>(spbf, Wgc, bgc, Wbi, bbi, ego32, egobf, k, flag);
    k_gather<<<2048, 256, 0, stream>>>(ego32, users, items, d_out, k + 1, 1, flag);
  }
}